// Round 26
// baseline (75036.151 us; speedup 1.0000x reference)
//
#include <hip/hip_runtime.h>

// R26: persistent kernel. 257 blocks x 256 threads, sense-reversing agent-scope
// grid barrier (design validated by R0==R1 bit-equality). Per step:
//  P1: blocks 0..255 hg=h@Wh^T (gsc-independent!), block 256: S/snorm/gic->gsc
//  P2: blocks 0..127 gates=xg+b+gsc*hg ->LN->cell->gco; 128..255 ys[t-1]=h*gsc
// Prologue (one-time): Wt, Wmt transposes; im,xg (bf16); nab for all rows.

constexpr int T_ = 256, B_ = 128;
constexpr int NBLK = 257;

typedef __attribute__((ext_vector_type(4))) float v4f;
typedef unsigned short u16;

__device__ __forceinline__ float sig_(float x) { return 1.f / (1.f + expf(-x)); }
__device__ __forceinline__ float bf2f(u16 u) { return __uint_as_float(((unsigned)u) << 16); }
__device__ __forceinline__ u16 f2bf(float f) {
  union { float f; unsigned u; } c;
  c.f = f;
  unsigned r = c.u + 0x7FFFu + ((c.u >> 16) & 1u);
  return (u16)(r >> 16);
}

__global__ void fill6f(float* __restrict__ o, long long n) {
  for (long long i = (long long)blockIdx.x * 256 + threadIdx.x; i < n;
       i += (long long)gridDim.x * 256)
    o[i] = 6.0f;
}

__global__ void tr_w(const float* __restrict__ W, float* __restrict__ Wt) {
  int i = blockIdx.x * 256 + threadIdx.x;
  if (i < 2048 * 1024) {
    int k = i >> 11, j = i & 2047;
    Wt[i] = W[(size_t)j * 1024 + k];
  }
}
__global__ void tr_wm(const float* __restrict__ Wm, float* __restrict__ Wmt) {
  int i = blockIdx.x * 256 + threadIdx.x;
  if (i < 512 * 512) {
    int k = i >> 9, j = i & 511;
    Wmt[i] = Wm[j * 512 + k];
  }
}

__global__ __launch_bounds__(256) void kim(const float* __restrict__ x,
                                           const float* __restrict__ Wmt,
                                           const float* __restrict__ bm,
                                           u16* __restrict__ im) {
  __shared__ float xs[32][512];
  const int rt = blockIdx.x >> 1, ct = blockIdx.x & 1, tid = threadIdx.x;
  const int r0 = rt * 32;
  for (int idx = tid; idx < 4096; idx += 256) {
    int rr = idx >> 7, cc = (idx & 127) * 4;
    *(v4f*)&xs[rr][cc] = *(const v4f*)(x + ((size_t)r0 + rr) * 512 + cc);
  }
  __syncthreads();
  const int col = ct * 256 + tid;
  float acc[32];
#pragma unroll
  for (int r = 0; r < 32; ++r) acc[r] = 0.f;
#pragma unroll 4
  for (int k = 0; k < 512; ++k) {
    float w = Wmt[(size_t)k * 512 + col];
#pragma unroll
    for (int r = 0; r < 32; ++r) acc[r] += xs[r][k] * w;
  }
  float bb = bm[col];
  for (int r = 0; r < 32; ++r) im[((size_t)r0 + r) * 512 + col] = f2bf(acc[r] + bb);
}

__global__ __launch_bounds__(256) void kxg(const float* __restrict__ x,
                                           const float* __restrict__ Wt,
                                           u16* __restrict__ xg) {
  __shared__ float xs[64][512];
  const int rt = blockIdx.x >> 3, ct = blockIdx.x & 7, tid = threadIdx.x;
  const size_t r0 = (size_t)rt * 64;
  for (int idx = tid; idx < 8192; idx += 256) {
    int rr = idx >> 7, cc = (idx & 127) * 4;
    *(v4f*)&xs[rr][cc] = *(const v4f*)(x + (r0 + rr) * 512 + cc);
  }
  __syncthreads();
  const int col = ct * 256 + tid;
  float acc[64];
#pragma unroll
  for (int r = 0; r < 64; ++r) acc[r] = 0.f;
#pragma unroll 2
  for (int k = 0; k < 512; ++k) {
    float w = Wt[(size_t)k * 2048 + col];
#pragma unroll
    for (int r = 0; r < 64; ++r) acc[r] += xs[r][k] * w;
  }
  for (int r = 0; r < 64; ++r) xg[(r0 + r) * 2048 + col] = f2bf(acc[r]);
}

// nab for all T*B rows (4 rows/block)
__global__ __launch_bounds__(256) void knab(const u16* __restrict__ im,
                                            float* __restrict__ nab) {
  int row = blockIdx.x * 4 + (threadIdx.x >> 6), l = threadIdx.x & 63;
  const u16* p = im + (size_t)row * 512 + l * 8;
  float s = 0.f;
#pragma unroll
  for (int j = 0; j < 8; ++j) { float f = bf2f(p[j]); s += f * f; }
#pragma unroll
  for (int m = 1; m < 64; m <<= 1) s += __shfl_xor(s, m, 64);
  if (l == 0) nab[row] = fmaxf(sqrtf(s), 1e-6f);
}

__device__ __forceinline__ void gbar(unsigned* cnt, unsigned* gen) {
  __threadfence();
  __syncthreads();
  if (threadIdx.x == 0) {
    unsigned g = __hip_atomic_load(gen, __ATOMIC_ACQUIRE, __HIP_MEMORY_SCOPE_AGENT);
    unsigned prev = __hip_atomic_fetch_add(cnt, 1u, __ATOMIC_ACQ_REL, __HIP_MEMORY_SCOPE_AGENT);
    if (prev == NBLK - 1) {
      __hip_atomic_store(cnt, 0u, __ATOMIC_RELAXED, __HIP_MEMORY_SCOPE_AGENT);
      __hip_atomic_store(gen, g + 1u, __ATOMIC_RELEASE, __HIP_MEMORY_SCOPE_AGENT);
    } else {
      while (__hip_atomic_load(gen, __ATOMIC_ACQUIRE, __HIP_MEMORY_SCOPE_AGENT) == g)
        __builtin_amdgcn_s_sleep(2);
    }
  }
  __syncthreads();
  __threadfence();
}

// persistent kernel
__global__ __launch_bounds__(256) void kP(
    const float* __restrict__ Wt,    // [1024,2048] k-major
    const u16* __restrict__ im,      // [T*B,512] bf16
    const u16* __restrict__ xg,      // [T*B,2048] bf16
    const float* __restrict__ bb,    // [2048]
    const float* __restrict__ lg,    // [2048]
    const float* __restrict__ lbta,  // [2048]
    const float* __restrict__ nab,   // [T*B]
    float* __restrict__ gco,         // [128]
    float* __restrict__ gsc,         // [128]
    float* __restrict__ cbuf,        // [128,512]
    float* __restrict__ hb,          // [2][128,512]
    float* __restrict__ hg,          // [128,2048]
    unsigned* __restrict__ bar,
    float* __restrict__ ys) {        // [T,B,512]
  __shared__ float lds[4096];        // 16KB: hstage / partial (GEMM), S (S-block)
  __shared__ float red[16];
  const int tid = threadIdx.x, bid = blockIdx.x;
  const int w = tid >> 6, l = tid & 63;

  for (int t = 0; t <= T_; ++t) {
    //---------------- phase 1 ----------------
    if (bid < 256) {
      if (t >= 1 && t < T_) {
        // hg tile: rows r0..r0+7, cols c0..c0+127; wave w = K-chunk 128
        const int rt = bid >> 4, ct = bid & 15;
        const int r0 = rt * 8, c0 = ct * 128;
        const float* hprev = hb + (size_t)((t - 1) & 1) * (128 * 512);
        // stage: hstage[w][r][k] = h[r0+r][w*128+k]
        float* hstage = lds;  // [4][8][128]
#pragma unroll
        for (int r = 0; r < 8; ++r) {
          hstage[(w * 8 + r) * 128 + l] = hprev[(size_t)(r0 + r) * 512 + w * 128 + l];
          hstage[(w * 8 + r) * 128 + l + 64] = hprev[(size_t)(r0 + r) * 512 + w * 128 + l + 64];
        }
        __syncthreads();
        float acc[8][2];
#pragma unroll
        for (int r = 0; r < 8; ++r) { acc[r][0] = 0.f; acc[r][1] = 0.f; }
        const int kbase = 512 + w * 128;
        for (int k = 0; k < 128; k += 4) {
          v4f hv[8];
#pragma unroll
          for (int r = 0; r < 8; ++r)
            hv[r] = *(const v4f*)&hstage[(w * 8 + r) * 128 + k];
#pragma unroll
          for (int u = 0; u < 4; ++u) {
            const float* wrow = Wt + (size_t)(kbase + k + u) * 2048 + c0;
            float wA = wrow[l], wB = wrow[l + 64];
#pragma unroll
            for (int r = 0; r < 8; ++r) {
              acc[r][0] += hv[r][u] * wA;
              acc[r][1] += hv[r][u] * wB;
            }
          }
        }
        __syncthreads();
        // cross-wave reduce via same LDS: partial[w][r][c]
#pragma unroll
        for (int r = 0; r < 8; ++r) {
          lds[(w * 8 + r) * 128 + l] = acc[r][0];
          lds[(w * 8 + r) * 128 + l + 64] = acc[r][1];
        }
        __syncthreads();
        // 1024 outputs / 256 threads = 4 each
#pragma unroll
        for (int o = 0; o < 4; ++o) {
          int idx = tid * 4 + o;
          int r = idx >> 7, cc = idx & 127;
          float s = lds[(0 * 8 + r) * 128 + cc] + lds[(1 * 8 + r) * 128 + cc] +
                    lds[(2 * 8 + r) * 128 + cc] + lds[(3 * 8 + r) * 128 + cc];
          hg[(size_t)(r0 + r) * 2048 + c0 + cc] = s;
        }
      }
    } else {
      // S-block: gsc for step t-1
      if (t >= 1) {
        float* S = lds;  // [512]
        float s0 = 0.f, s1 = 0.f;
        for (int p = 0; p < B_; ++p) {
          s0 += cbuf[(size_t)p * 512 + tid];
          s1 += cbuf[(size_t)p * 512 + tid + 256];
        }
        S[tid] = s0;
        S[tid + 256] = s1;
        float v = s0 * s0 + s1 * s1;
#pragma unroll
        for (int m = 1; m < 64; m <<= 1) v += __shfl_xor(v, m, 64);
        if (l == 0) red[w] = v;
        __syncthreads();
        float snorm = fmaxf(sqrtf(red[0] + red[1] + red[2] + red[3]) * (1.f / 128.f), 1e-6f);
        // dots: r = tid>>1, half q
        const int r = tid >> 1, q = tid & 1;
        const u16* ir = im + ((size_t)(t - 1) * B_ + r) * 512 + q * 256;
        const float* Sq = S + q * 256;
        float d = 0.f;
#pragma unroll 8
        for (int j = 0; j < 256; ++j) d += bf2f(ir[j]) * Sq[j];
        d += __shfl_xor(d, 1, 64);
        if (q == 0) {
          float cosv = (d * (1.f / 128.f)) / (nab[(size_t)(t - 1) * B_ + r] * snorm);
          gsc[r] = sig_((cosv + 1.f) * 0.5f) + gco[r];
        }
      }
    }
    gbar(bar, bar + 1);
    //---------------- phase 2 ----------------
    if (bid < 128) {
      if (t < T_) {
        const int row = bid;
        const float gs = (t == 0) ? 0.f : gsc[row];
        const u16* xgr = xg + ((size_t)t * B_ + row) * 2048;
        const float* hgr = hg + (size_t)row * 2048;
        float a4[4][2];
#pragma unroll
        for (int G = 0; G < 4; ++G) {
          const int g0 = G * 512 + tid, g1 = G * 512 + tid + 256;
          float v0 = bf2f(xgr[g0]) + bb[g0];
          float v1 = bf2f(xgr[g1]) + bb[g1];
          if (t > 0) {
            v0 += gs * hgr[g0];
            v1 += gs * hgr[g1];
          }
          float s = v0 + v1, sq = v0 * v0 + v1 * v1;
#pragma unroll
          for (int m = 1; m < 64; m <<= 1) {
            s += __shfl_xor(s, m, 64);
            sq += __shfl_xor(sq, m, 64);
          }
          if (l == 0) { red[w] = s; red[4 + w] = sq; }
          __syncthreads();
          float st = red[0] + red[1] + red[2] + red[3];
          float sqt = red[4] + red[5] + red[6] + red[7];
          __syncthreads();
          float mu = st * (1.f / 512.f);
          float var = sqt * (1.f / 512.f) - mu * mu;
          float rs = rsqrtf(var + 1e-5f);
          float z0 = (v0 - mu) * rs * lg[g0] + lbta[g0];
          float z1 = (v1 - mu) * rs * lg[g1] + lbta[g1];
          a4[G][0] = (G == 2) ? tanhf(z0) : sig_(z0);
          a4[G][1] = (G == 2) ? tanhf(z1) : sig_(z1);
        }
        const size_t rb = (size_t)row * 512;
        float* hcur = hb + (size_t)(t & 1) * (128 * 512);
        float cp0 = (t == 0) ? 0.f : cbuf[rb + tid];
        float cp1 = (t == 0) ? 0.f : cbuf[rb + tid + 256];
        float cn0 = a4[1][0] * cp0 + a4[0][0] * a4[2][0];
        float cn1 = a4[1][1] * cp1 + a4[0][1] * a4[2][1];
        float hh0 = a4[3][0] * tanhf(cn0);
        float hh1 = a4[3][1] * tanhf(cn1);
        cbuf[rb + tid] = cn0;
        cbuf[rb + tid + 256] = cn1;
        hcur[rb + tid] = hh0;
        hcur[rb + tid + 256] = hh1;
        const u16* ir = im + ((size_t)t * B_ + row) * 512;
        float i0 = bf2f(ir[tid]), i1 = bf2f(ir[tid + 256]);
        float hn = hh0 * hh0 + hh1 * hh1;
        float dih = i0 * hh0 + i1 * hh1;
#pragma unroll
        for (int m = 1; m < 64; m <<= 1) {
          hn += __shfl_xor(hn, m, 64);
          dih += __shfl_xor(dih, m, 64);
        }
        if (l == 0) { red[8 + w] = hn; red[12 + w] = dih; }
        __syncthreads();
        if (tid == 0) {
          float hnt = red[8] + red[9] + red[10] + red[11];
          float dt = red[12] + red[13] + red[14] + red[15];
          float na = nab[(size_t)t * B_ + row];
          float nc = fmaxf(sqrtf(hnt), 1e-6f);
          gco[row] = sig_((dt / (na * nc) + 1.f) * 0.5f);
        }
      }
    } else if (bid < 256) {
      if (t >= 1) {
        const int row = bid - 128;
        const float gs = gsc[row];
        const float* hprev = hb + (size_t)((t - 1) & 1) * (128 * 512);
        float* yr = ys + ((size_t)(t - 1) * B_ + row) * 512;
        yr[tid] = hprev[(size_t)row * 512 + tid] * gs;
        yr[tid + 256] = hprev[(size_t)row * 512 + tid + 256] * gs;
      }
    }
    gbar(bar, bar + 1);
  }
}

namespace w26 {
constexpr size_t WT = 0;
constexpr size_t WT_SZ = (size_t)1024 * 2048 * 4;       // 8 MB
constexpr size_t IMB = WT + WT_SZ;
constexpr size_t IMB_SZ = (size_t)T_ * B_ * 512 * 2;    // 32 MB
constexpr size_t XG = IMB + IMB_SZ;
constexpr size_t XG_SZ = (size_t)T_ * B_ * 2048 * 2;    // 128 MB
constexpr size_t HG = XG + XG_SZ;
constexpr size_t HG_SZ = (size_t)B_ * 2048 * 4;         // 1 MB
constexpr size_t CB = HG + HG_SZ;
constexpr size_t CB_SZ = (size_t)B_ * 512 * 4;
constexpr size_t HB = CB + CB_SZ;
constexpr size_t HB_SZ = (size_t)2 * B_ * 512 * 4;
constexpr size_t NAB = HB + HB_SZ;
constexpr size_t NAB_SZ = (size_t)T_ * B_ * 4;          // 128 KB
constexpr size_t GCO = NAB + NAB_SZ;
constexpr size_t GSC = GCO + 4096;
constexpr size_t BAR = GSC + 4096;
constexpr size_t WMT = BAR + 4096;
constexpr size_t WMT_SZ = (size_t)512 * 512 * 4;
constexpr size_t NEED = WMT + WMT_SZ + 1024;            // ~171 MB
}

extern "C" void kernel_launch(void* const* d_in, const int* in_sizes, int n_in,
                              void* d_out, int out_size, void* d_ws, size_t ws_size,
                              hipStream_t stream) {
  float* ys = (float*)d_out;
  long long ncap = (long long)out_size;
  if (ncap > 16777216LL) ncap = 16777216LL;

  if (n_in < 7 || ws_size < w26::NEED) {
    fill6f<<<2048, 256, 0, stream>>>(ys, ncap);
    return;
  }

  const float* x = (const float*)d_in[0];
  const float* W = (const float*)d_in[1];
  const float* bb = (const float*)d_in[2];
  const float* Wm = (const float*)d_in[3];
  const float* bm = (const float*)d_in[4];
  const float* lg = (const float*)d_in[5];
  const float* lbta = (const float*)d_in[6];

  char* ws = (char*)d_ws;
  float* Wt = (float*)(ws + w26::WT);
  u16* im = (u16*)(ws + w26::IMB);
  u16* xg = (u16*)(ws + w26::XG);
  float* hg = (float*)(ws + w26::HG);
  float* cbuf = (float*)(ws + w26::CB);
  float* hb = (float*)(ws + w26::HB);
  float* nab = (float*)(ws + w26::NAB);
  float* gco = (float*)(ws + w26::GCO);
  float* gsc = (float*)(ws + w26::GSC);
  unsigned* bar = (unsigned*)(ws + w26::BAR);
  float* Wmt = (float*)(ws + w26::WMT);

  hipMemsetAsync(bar, 0, 64, stream);
  tr_w<<<8192, 256, 0, stream>>>(W, Wt);
  tr_wm<<<1024, 256, 0, stream>>>(Wm, Wmt);
  kim<<<2048, 256, 0, stream>>>(x, Wmt, bm, im);
  kxg<<<4096, 256, 0, stream>>>(x, Wt, xg);
  knab<<<8192, 256, 0, stream>>>(im, nab);

  kP<<<NBLK, 256, 0, stream>>>(Wt, im, xg, bb, lg, lbta, nab,
                               gco, gsc, cbuf, hb, hg, bar, ys);
}